// Round 6
// baseline (515.332 us; speedup 1.0000x reference)
//
#include <hip/hip_runtime.h>

// GestureRNN v6: two-pass (xp precompute to d_ws) + fenceless f16 recurrence.
// B=4096, T=512, IN=10, H=32, NCLS=9.
//
// Post-mortem lineage: v1/v4/v5 showed wall time = 511 x per-step critical
// latency (each wave runs its own serial chain; extra waves don't shorten it).
// v6 removes two latency segments from the chain:
//  (1) x-projection moves to a separate memory-bound pass writing
//      xp[b][h][t] (f16, T-contiguous) into d_ws; the recurrent loop reads
//      16 B per 8 steps, prefetched one full group (~2400 cyc) ahead.
//  (2) __syncthreads() -> compiler-only fence. Single-wave workgroups + the
//      LDS pipe's per-wave in-order execution guarantee RAW through LDS
//      without draining lgkmcnt(0) before the reads.
// Core stays v5: f16 state in LDS (8 ds_read_b128/step), v_dot2_f32_f16 with
// half2-packed weights in VGPRs, layer-pipelined (step i computes h1[i] and
// h2[i-1] from the same published state).

constexpr int T_  = 512;
constexpr int IN_ = 10;
constexpr int H_  = 32;
constexpr int NC_ = 9;

typedef _Float16 h2v __attribute__((ext_vector_type(2)));
union U4H { uint4 u; h2v h[4]; };
union U4F { uint4 u; _Float16 f[8]; };

__device__ __forceinline__ void wave_fence() {
    // compiler memory fence + scheduling barrier; no ISA instruction emitted.
    // HW ordering of ds_write -> ds_read is the per-wave in-order DS pipe.
    __asm__ volatile("" ::: "memory");
    __builtin_amdgcn_wave_barrier();
    __asm__ volatile("" ::: "memory");
}

// ---------------- pass 1: xp[b][j][t] = bias0[j] + W_ih0[j,:].x[b,t,:] ----
__global__ __launch_bounds__(256) void xproj_kernel(
    const float* __restrict__ x,      // [B, T, IN]
    const float* __restrict__ W_ih0,  // [H, IN]
    const float* __restrict__ b_ih0,  // [H]
    const float* __restrict__ b_hh0,  // [H]
    _Float16* __restrict__ xp)        // [B, H, T]
{
    // tid -> (b, j, t8): consecutive tid = consecutive t8 -> coalesced writes
    const int tid = blockIdx.x * 256 + threadIdx.x;
    const int t8  = tid & 63;          // timestep group (8 steps)
    const int j   = (tid >> 6) & 31;   // hidden unit
    const int b   = tid >> 11;         // batch

    float w[IN_];
#pragma unroll
    for (int i = 0; i < IN_; ++i) w[i] = W_ih0[j * IN_ + i];
    const float bias = b_ih0[j] + b_hh0[j];

    // 8 timesteps x 10 floats = 80 floats = 320 B, 16B-aligned, contiguous
    const float4* xs = (const float4*)(x + ((size_t)b * T_ + t8 * 8) * IN_);
    float f[80];
#pragma unroll
    for (int q = 0; q < 20; ++q) ((float4*)f)[q] = xs[q];

    U4F o;
#pragma unroll
    for (int r = 0; r < 8; ++r) {
        float a = bias;
#pragma unroll
        for (int i = 0; i < IN_; ++i) a = fmaf(w[i], f[r * IN_ + i], a);
        o.f[r] = (_Float16)a;
    }
    *(uint4*)(xp + ((size_t)b * H_ + j) * T_ + t8 * 8) = o.u;
}

// ---------------- pass 2: fenceless recurrent loop ------------------------
#define STEP(XV)                                                             \
    {                                                                        \
        const uint4* sp = (const uint4*)&hs[g][0];                           \
        h2v h1h[16], h2h[16];                                                \
        _Pragma("unroll")                                                    \
        for (int q = 0; q < 4; ++q) {                                        \
            U4H a; a.u = sp[q];                                              \
            U4H c; c.u = sp[q + 4];                                          \
            _Pragma("unroll")                                                \
            for (int r = 0; r < 4; ++r) {                                    \
                h1h[4 * q + r] = a.h[r];                                     \
                h2h[4 * q + r] = c.h[r];                                     \
            }                                                                \
        }                                                                    \
        float a1A = (XV), a1B = 0.f;                                         \
        float a2A = bias1, a2B = 0.f, a2C = 0.f, a2D = 0.f;                  \
        _Pragma("unroll")                                                    \
        for (int k = 0; k < 8; ++k) {                                        \
            a1A = __builtin_amdgcn_fdot2(w0[k],     h1h[k],     a1A, false); \
            a1B = __builtin_amdgcn_fdot2(w0[k + 8], h1h[k + 8], a1B, false); \
            a2A = __builtin_amdgcn_fdot2(w1[k],     h1h[k],     a2A, false); \
            a2B = __builtin_amdgcn_fdot2(w1[k + 8], h1h[k + 8], a2B, false); \
            a2C = __builtin_amdgcn_fdot2(w2[k],     h2h[k],     a2C, false); \
            a2D = __builtin_amdgcn_fdot2(w2[k + 8], h2h[k + 8], a2D, false); \
        }                                                                    \
        const float nh1 = fmaxf(a1A + a1B, 0.f);                             \
        const float nh2 = fmaxf((a2A + a2B) + (a2C + a2D), 0.f);             \
        hs[g][j]      = (_Float16)nh1;                                       \
        hs[g][H_ + j] = (_Float16)nh2;                                       \
        wave_fence();                                                        \
    }

__global__ __launch_bounds__(64, 1) void rnn_kernel(
    const _Float16* __restrict__ xp,  // [B, H, T]
    const float* __restrict__ W_hh0,  // [H, H]
    const float* __restrict__ W_ih1,  // [H, H]
    const float* __restrict__ W_hh1,  // [H, H]
    const float* __restrict__ b_ih1,  // [H]
    const float* __restrict__ b_hh1,  // [H]
    const float* __restrict__ W_fc,   // [NC, H]
    const float* __restrict__ b_fc,   // [NC]
    float* __restrict__ out)          // [B, NC]
{
    const int lane = threadIdx.x;
    const int g    = lane >> 5;       // batch element within wave
    const int j    = lane & 31;       // hidden unit owned by this lane
    const long b   = (long)blockIdx.x * 2 + g;

    // half2-packed recurrent weight rows for unit j
    h2v w0[16], w1[16], w2[16];
#pragma unroll
    for (int k = 0; k < 16; ++k) {
        w0[k][0] = (_Float16)W_hh0[j * H_ + 2 * k];
        w0[k][1] = (_Float16)W_hh0[j * H_ + 2 * k + 1];
        w1[k][0] = (_Float16)W_ih1[j * H_ + 2 * k];
        w1[k][1] = (_Float16)W_ih1[j * H_ + 2 * k + 1];
        w2[k][0] = (_Float16)W_hh1[j * H_ + 2 * k];
        w2[k][1] = (_Float16)W_hh1[j * H_ + 2 * k + 1];
    }
    const float bias1 = b_ih1[j] + b_hh1[j];

    // state (f16): hs[g][0..31] = h1, hs[g][32..63] = h2
    __shared__ __align__(16) _Float16 hs[2][2 * H_];

    // xp row for (b, j): T_ f16, 16B-aligned; one uint4 = 8 timesteps
    const uint4* xr4 = (const uint4*)(xp + ((size_t)b * H_ + j) * T_);

    float xf[8];
    uint4 nxt;
    {
        U4F c; c.u = xr4[0];
        nxt = xr4[1];                  // prefetch group 1
#pragma unroll
        for (int r = 0; r < 8; ++r) xf[r] = (float)c.f[r];
    }

    // prologue: h1[0] = relu(xp[0]) (xp includes bias0), h2[-1] = 0
    hs[g][j]      = (_Float16)fmaxf(xf[0], 0.f);
    hs[g][H_ + j] = (_Float16)0.f;
    wave_fence();

    // steps 1..7 (group 0)
#pragma unroll
    for (int r = 1; r < 8; ++r) STEP(xf[r]);

    // groups 1..63: steps 8*g8 .. 8*g8+7
#pragma unroll 1
    for (int g8 = 1; g8 < 64; ++g8) {
        U4F c; c.u = nxt;
        if (g8 < 63) nxt = xr4[g8 + 1];    // prefetch ~8 steps ahead
#pragma unroll
        for (int r = 0; r < 8; ++r) xf[r] = (float)c.f[r];
#pragma unroll
        for (int r = 0; r < 8; ++r) STEP(xf[r]);
    }

    // epilogue: h2[511] = relu(bias1 + W_ih1.h1[511] + W_hh1.h2[510])
    {
        float aA = bias1, aB = 0.f, aC = 0.f, aD = 0.f;
#pragma unroll
        for (int k = 0; k < 16; ++k) {
            aA = fmaf(W_ih1[j * H_ + k],      (float)hs[g][k],           aA);
            aB = fmaf(W_ih1[j * H_ + k + 16], (float)hs[g][k + 16],      aB);
            aC = fmaf(W_hh1[j * H_ + k],      (float)hs[g][H_ + k],      aC);
            aD = fmaf(W_hh1[j * H_ + k + 16], (float)hs[g][H_ + k + 16], aD);
        }
        const float nh2 = fmaxf((aA + aB) + (aC + aD), 0.f);
        __syncthreads();
        hs[g][H_ + j] = (_Float16)nh2;
    }
    __syncthreads();

    // FC head: out[b, c] = W_fc[c,:].h2[511] + b_fc[c]
    if (j < NC_) {
        float acc = b_fc[j];
#pragma unroll
        for (int k = 0; k < H_; ++k)
            acc = fmaf(W_fc[j * H_ + k], (float)hs[g][H_ + k], acc);
        out[b * NC_ + j] = acc;
    }
}

// ---------------- fallback (v5, proven 242 us) if ws too small ------------
__global__ __launch_bounds__(64, 1) void rnn_fallback(
    const float* __restrict__ x, const float* __restrict__ W_ih0,
    const float* __restrict__ W_hh0, const float* __restrict__ b_ih0,
    const float* __restrict__ b_hh0, const float* __restrict__ W_ih1,
    const float* __restrict__ W_hh1, const float* __restrict__ b_ih1,
    const float* __restrict__ b_hh1, const float* __restrict__ W_fc,
    const float* __restrict__ b_fc, float* __restrict__ out)
{
    const int lane = threadIdx.x;
    const int g    = lane >> 5;
    const int j    = lane & 31;
    const long b   = (long)blockIdx.x * 2 + g;

    float wx[IN_];
#pragma unroll
    for (int i = 0; i < IN_; ++i) wx[i] = W_ih0[j * IN_ + i];
    h2v w0[16], w1[16], w2[16];
#pragma unroll
    for (int k = 0; k < 16; ++k) {
        w0[k][0] = (_Float16)W_hh0[j * H_ + 2 * k];
        w0[k][1] = (_Float16)W_hh0[j * H_ + 2 * k + 1];
        w1[k][0] = (_Float16)W_ih1[j * H_ + 2 * k];
        w1[k][1] = (_Float16)W_ih1[j * H_ + 2 * k + 1];
        w2[k][0] = (_Float16)W_hh1[j * H_ + 2 * k];
        w2[k][1] = (_Float16)W_hh1[j * H_ + 2 * k + 1];
    }
    const float bias0 = b_ih0[j] + b_hh0[j];
    const float bias1 = b_ih1[j] + b_hh1[j];

    __shared__ __align__(16) _Float16 hs[2][2 * H_];

    const float* xptr = x + (size_t)b * T_ * IN_;
    float xv[IN_];
#pragma unroll
    for (int i = 0; i < IN_; i += 2) {
        float2 v = *(const float2*)(xptr + i);
        xv[i] = v.x; xv[i + 1] = v.y;
    }
    {
        float a = bias0;
#pragma unroll
        for (int i = 0; i < IN_; ++i) a = fmaf(wx[i], xv[i], a);
        hs[g][j]      = (_Float16)fmaxf(a, 0.f);
        hs[g][H_ + j] = (_Float16)0.f;
    }
    __syncthreads();
    xptr += IN_;
#pragma unroll
    for (int i = 0; i < IN_; i += 2) {
        float2 v = *(const float2*)(xptr + i);
        xv[i] = v.x; xv[i + 1] = v.y;
    }
#pragma unroll 1
    for (int i = 1; i < T_; ++i) {
        h2v h1h[16], h2h[16];
        {
            const uint4* sp = (const uint4*)&hs[g][0];
#pragma unroll
            for (int q = 0; q < 4; ++q) {
                U4H a; a.u = sp[q];
                U4H c; c.u = sp[q + 4];
#pragma unroll
                for (int r = 0; r < 4; ++r) {
                    h1h[4 * q + r] = a.h[r];
                    h2h[4 * q + r] = c.h[r];
                }
            }
        }
        float a1A = bias0, a1B = 0.f;
#pragma unroll
        for (int i2 = 0; i2 < IN_; i2 += 2) {
            a1A = fmaf(wx[i2],     xv[i2],     a1A);
            a1B = fmaf(wx[i2 + 1], xv[i2 + 1], a1B);
        }
        float a2A = bias1, a2B = 0.f, a2C = 0.f, a2D = 0.f;
#pragma unroll
        for (int k = 0; k < 8; ++k) {
            a1A = __builtin_amdgcn_fdot2(w0[k],     h1h[k],     a1A, false);
            a1B = __builtin_amdgcn_fdot2(w0[k + 8], h1h[k + 8], a1B, false);
            a2A = __builtin_amdgcn_fdot2(w1[k],     h1h[k],     a2A, false);
            a2B = __builtin_amdgcn_fdot2(w1[k + 8], h1h[k + 8], a2B, false);
            a2C = __builtin_amdgcn_fdot2(w2[k],     h2h[k],     a2C, false);
            a2D = __builtin_amdgcn_fdot2(w2[k + 8], h2h[k + 8], a2D, false);
        }
        if (i + 1 < T_) {
            xptr += IN_;
#pragma unroll
            for (int i2 = 0; i2 < IN_; i2 += 2) {
                float2 v = *(const float2*)(xptr + i2);
                xv[i2] = v.x; xv[i2 + 1] = v.y;
            }
        }
        const float nh1 = fmaxf(a1A + a1B, 0.f);
        const float nh2 = fmaxf((a2A + a2B) + (a2C + a2D), 0.f);
        hs[g][j]      = (_Float16)nh1;
        hs[g][H_ + j] = (_Float16)nh2;
        __syncthreads();
    }
    {
        float aA = bias1, aB = 0.f, aC = 0.f, aD = 0.f;
#pragma unroll
        for (int k = 0; k < 16; ++k) {
            aA = fmaf(W_ih1[j * H_ + k],      (float)hs[g][k],           aA);
            aB = fmaf(W_ih1[j * H_ + k + 16], (float)hs[g][k + 16],      aB);
            aC = fmaf(W_hh1[j * H_ + k],      (float)hs[g][H_ + k],      aC);
            aD = fmaf(W_hh1[j * H_ + k + 16], (float)hs[g][H_ + k + 16], aD);
        }
        const float nh2 = fmaxf((aA + aB) + (aC + aD), 0.f);
        __syncthreads();
        hs[g][H_ + j] = (_Float16)nh2;
    }
    __syncthreads();
    if (j < NC_) {
        float acc = b_fc[j];
#pragma unroll
        for (int k = 0; k < H_; ++k)
            acc = fmaf(W_fc[j * H_ + k], (float)hs[g][H_ + k], acc);
        out[b * NC_ + j] = acc;
    }
}

extern "C" void kernel_launch(void* const* d_in, const int* in_sizes, int n_in,
                              void* d_out, int out_size, void* d_ws, size_t ws_size,
                              hipStream_t stream) {
    const float* x     = (const float*)d_in[0];
    const float* W_ih0 = (const float*)d_in[1];
    const float* W_hh0 = (const float*)d_in[2];
    const float* b_ih0 = (const float*)d_in[3];
    const float* b_hh0 = (const float*)d_in[4];
    const float* W_ih1 = (const float*)d_in[5];
    const float* W_hh1 = (const float*)d_in[6];
    const float* b_ih1 = (const float*)d_in[7];
    const float* b_hh1 = (const float*)d_in[8];
    const float* W_fc  = (const float*)d_in[9];
    const float* b_fc  = (const float*)d_in[10];
    float* out = (float*)d_out;

    const int B = in_sizes[0] / (T_ * IN_);   // 4096
    const size_t need = (size_t)B * H_ * T_ * sizeof(_Float16);  // 134 MB

    if (ws_size >= need) {
        _Float16* xp = (_Float16*)d_ws;
        xproj_kernel<<<dim3(B * 8), dim3(256), 0, stream>>>(
            x, W_ih0, b_ih0, b_hh0, xp);
        rnn_kernel<<<dim3(B / 2), dim3(64), 0, stream>>>(
            xp, W_hh0, W_ih1, W_hh1, b_ih1, b_hh1, W_fc, b_fc, out);
    } else {
        rnn_fallback<<<dim3(B / 2), dim3(64), 0, stream>>>(
            x, W_ih0, W_hh0, b_ih0, b_hh0, W_ih1, W_hh1, b_ih1, b_hh1,
            W_fc, b_fc, out);
    }
}

// Round 7
// 327.340 us; speedup vs baseline: 1.5743x; 1.5743x over previous
//
#include <hip/hip_runtime.h>

// GestureRNN v7: 4 batches/wave, 2 units/lane. B=4096, T=512, IN=10, H=32.
// v5/v6 post-mortem: per-CU-step cost ~= VALU-issue bound (waves/SIMD x instr
// x 2cyc) overlapped with DS. v7 amortizes: 16 lanes per batch, lane owns
// units {2u,2u+1} -> same per-wave DS (8 ds_read_b128 + 2 b32 writes) and
// ~140 VALU instr now serve 4 batches (v5: 2). Grid 1024 single-wave blocks
// -> 1 wave/SIMD; bet: shorter per-step critical path beats lost TLP.
// LDS state stride padded to 144 B so the 4 batch-groups' broadcast reads hit
// disjoint bank quartets (conflict-free). f16 state + v_dot2_f32_f16 (proven
// absmax 2e-3). Layer-pipelined (step t computes h1[t], h2[t-1]). Barrier
// kept (v6 showed fenceless does not help; single-wave blocks make it cheap).

constexpr int T_  = 512;
constexpr int IN_ = 10;
constexpr int H_  = 32;
constexpr int NC_ = 9;
constexpr int SP_ = 72;   // padded per-batch state stride (f16 elems) = 144 B

typedef _Float16 h2v __attribute__((ext_vector_type(2)));
union U4H { uint4 u; h2v h[4]; };

__global__ __launch_bounds__(64, 1) void gesture_rnn_kernel(
    const float* __restrict__ x,      // [B, T, IN]
    const float* __restrict__ W_ih0,  // [H, IN]
    const float* __restrict__ W_hh0,  // [H, H]
    const float* __restrict__ b_ih0,  // [H]
    const float* __restrict__ b_hh0,  // [H]
    const float* __restrict__ W_ih1,  // [H, H]
    const float* __restrict__ W_hh1,  // [H, H]
    const float* __restrict__ b_ih1,  // [H]
    const float* __restrict__ b_hh1,  // [H]
    const float* __restrict__ W_fc,   // [NC, H]
    const float* __restrict__ b_fc,   // [NC]
    float* __restrict__ out)          // [B, NC]
{
    const int lane = threadIdx.x;     // 0..63
    const int bs   = lane >> 4;       // batch slot within wave: 0..3
    const int u    = lane & 15;       // unit-pair index: owns units 2u, 2u+1
    const long b   = (long)blockIdx.x * 4 + bs;
    const int jA   = 2 * u, jB = 2 * u + 1;

    // ---- fp32 x-projection weights for both owned units ----
    float wxA[IN_], wxB[IN_];
#pragma unroll
    for (int i = 0; i < IN_; ++i) {
        wxA[i] = W_ih0[jA * IN_ + i];
        wxB[i] = W_ih0[jB * IN_ + i];
    }

    // ---- half2-packed recurrent weight rows for units jA, jB ----
    h2v w0a[16], w0b[16], w1a[16], w1b[16], w2a[16], w2b[16];
#pragma unroll
    for (int k = 0; k < 16; ++k) {
        w0a[k][0] = (_Float16)W_hh0[jA * H_ + 2 * k];
        w0a[k][1] = (_Float16)W_hh0[jA * H_ + 2 * k + 1];
        w0b[k][0] = (_Float16)W_hh0[jB * H_ + 2 * k];
        w0b[k][1] = (_Float16)W_hh0[jB * H_ + 2 * k + 1];
        w1a[k][0] = (_Float16)W_ih1[jA * H_ + 2 * k];
        w1a[k][1] = (_Float16)W_ih1[jA * H_ + 2 * k + 1];
        w1b[k][0] = (_Float16)W_ih1[jB * H_ + 2 * k];
        w1b[k][1] = (_Float16)W_ih1[jB * H_ + 2 * k + 1];
        w2a[k][0] = (_Float16)W_hh1[jA * H_ + 2 * k];
        w2a[k][1] = (_Float16)W_hh1[jA * H_ + 2 * k + 1];
        w2b[k][0] = (_Float16)W_hh1[jB * H_ + 2 * k];
        w2b[k][1] = (_Float16)W_hh1[jB * H_ + 2 * k + 1];
    }
    const float bias0A = b_ih0[jA] + b_hh0[jA];
    const float bias0B = b_ih0[jB] + b_hh0[jB];
    const float bias1A = b_ih1[jA] + b_hh1[jA];
    const float bias1B = b_ih1[jB] + b_hh1[jB];

    // state (f16): hs[bs][0..31] = h1, hs[bs][32..63] = h2; stride 72 pads
    // the 4 batch slots onto disjoint bank quartets for the broadcast reads.
    __shared__ __align__(16) _Float16 hs[4][SP_];

    const float* xptr = x + (size_t)b * T_ * IN_;
    float xv[IN_];
#pragma unroll
    for (int i = 0; i < IN_; i += 2) {
        float2 v = *(const float2*)(xptr + i);
        xv[i] = v.x; xv[i + 1] = v.y;
    }

    // ---- prologue: h1[0] = relu(xproj(x[0])), h2[-1] = 0 ----
    {
        float aA = bias0A, aB = bias0B;
#pragma unroll
        for (int i = 0; i < IN_; ++i) {
            aA = fmaf(wxA[i], xv[i], aA);
            aB = fmaf(wxB[i], xv[i], aB);
        }
        h2v p; p[0] = (_Float16)fmaxf(aA, 0.f); p[1] = (_Float16)fmaxf(aB, 0.f);
        *(h2v*)&hs[bs][2 * u] = p;
        h2v z; z[0] = (_Float16)0.f; z[1] = (_Float16)0.f;
        *(h2v*)&hs[bs][H_ + 2 * u] = z;
    }
    __syncthreads();

    // preload x[1]
    xptr += IN_;
#pragma unroll
    for (int i = 0; i < IN_; i += 2) {
        float2 v = *(const float2*)(xptr + i);
        xv[i] = v.x; xv[i + 1] = v.y;
    }

    // ---- main loop: step t computes h1[t] and h2[t-1] ----
#pragma unroll 1
    for (int t = 1; t < T_; ++t) {
        // read own batch's state: 8x ds_read_b128, broadcast within group
        h2v h1h[16], h2h[16];
        {
            const uint4* sp = (const uint4*)&hs[bs][0];
#pragma unroll
            for (int q = 0; q < 4; ++q) {
                U4H a; a.u = sp[q];
                U4H c; c.u = sp[q + 4];
#pragma unroll
                for (int r = 0; r < 4; ++r) {
                    h1h[4 * q + r] = a.h[r];
                    h2h[4 * q + r] = c.h[r];
                }
            }
        }

        // layer-0 x-projection (fp32) for both units
        float a1A0 = bias0A, a1A1 = 0.f, a1B0 = bias0B, a1B1 = 0.f;
#pragma unroll
        for (int i = 0; i < IN_; i += 2) {
            a1A0 = fmaf(wxA[i],     xv[i],     a1A0);
            a1A1 = fmaf(wxA[i + 1], xv[i + 1], a1A1);
            a1B0 = fmaf(wxB[i],     xv[i],     a1B0);
            a1B1 = fmaf(wxB[i + 1], xv[i + 1], a1B1);
        }

        // 96 fdot2: h1 dots (16/unit) + h2-lagged layer-1 dots (32/unit)
        float a2A0 = bias1A, a2A1 = 0.f, a2A2 = 0.f, a2A3 = 0.f;
        float a2B0 = bias1B, a2B1 = 0.f, a2B2 = 0.f, a2B3 = 0.f;
#pragma unroll
        for (int k = 0; k < 8; ++k) {
            a1A0 = __builtin_amdgcn_fdot2(w0a[k],     h1h[k],     a1A0, false);
            a1A1 = __builtin_amdgcn_fdot2(w0a[k + 8], h1h[k + 8], a1A1, false);
            a1B0 = __builtin_amdgcn_fdot2(w0b[k],     h1h[k],     a1B0, false);
            a1B1 = __builtin_amdgcn_fdot2(w0b[k + 8], h1h[k + 8], a1B1, false);
            a2A0 = __builtin_amdgcn_fdot2(w1a[k],     h1h[k],     a2A0, false);
            a2A1 = __builtin_amdgcn_fdot2(w1a[k + 8], h1h[k + 8], a2A1, false);
            a2A2 = __builtin_amdgcn_fdot2(w2a[k],     h2h[k],     a2A2, false);
            a2A3 = __builtin_amdgcn_fdot2(w2a[k + 8], h2h[k + 8], a2A3, false);
            a2B0 = __builtin_amdgcn_fdot2(w1b[k],     h1h[k],     a2B0, false);
            a2B1 = __builtin_amdgcn_fdot2(w1b[k + 8], h1h[k + 8], a2B1, false);
            a2B2 = __builtin_amdgcn_fdot2(w2b[k],     h2h[k],     a2B2, false);
            a2B3 = __builtin_amdgcn_fdot2(w2b[k + 8], h2h[k + 8], a2B3, false);
        }

        // prefetch next x while dots finish
        if (t + 1 < T_) {
            xptr += IN_;
#pragma unroll
            for (int i = 0; i < IN_; i += 2) {
                float2 v = *(const float2*)(xptr + i);
                xv[i] = v.x; xv[i + 1] = v.y;
            }
        }

        const float nh1A = fmaxf(a1A0 + a1A1, 0.f);
        const float nh1B = fmaxf(a1B0 + a1B1, 0.f);
        const float nh2A = fmaxf((a2A0 + a2A1) + (a2A2 + a2A3), 0.f);
        const float nh2B = fmaxf((a2B0 + a2B1) + (a2B2 + a2B3), 0.f);

        h2v p1; p1[0] = (_Float16)nh1A; p1[1] = (_Float16)nh1B;
        h2v p2; p2[0] = (_Float16)nh2A; p2[1] = (_Float16)nh2B;
        *(h2v*)&hs[bs][2 * u]       = p1;   // 2x ds_write_b32
        *(h2v*)&hs[bs][H_ + 2 * u]  = p2;
        __syncthreads();
    }

    // ---- epilogue: h2[511] = relu(bias1 + W_ih1.h1[511] + W_hh1.h2[510]) ----
    {
        h2v h1h[16], h2h[16];
        {
            const uint4* sp = (const uint4*)&hs[bs][0];
#pragma unroll
            for (int q = 0; q < 4; ++q) {
                U4H a; a.u = sp[q];
                U4H c; c.u = sp[q + 4];
#pragma unroll
                for (int r = 0; r < 4; ++r) {
                    h1h[4 * q + r] = a.h[r];
                    h2h[4 * q + r] = c.h[r];
                }
            }
        }
        float a2A0 = bias1A, a2A1 = 0.f, a2A2 = 0.f, a2A3 = 0.f;
        float a2B0 = bias1B, a2B1 = 0.f, a2B2 = 0.f, a2B3 = 0.f;
#pragma unroll
        for (int k = 0; k < 8; ++k) {
            a2A0 = __builtin_amdgcn_fdot2(w1a[k],     h1h[k],     a2A0, false);
            a2A1 = __builtin_amdgcn_fdot2(w1a[k + 8], h1h[k + 8], a2A1, false);
            a2A2 = __builtin_amdgcn_fdot2(w2a[k],     h2h[k],     a2A2, false);
            a2A3 = __builtin_amdgcn_fdot2(w2a[k + 8], h2h[k + 8], a2A3, false);
            a2B0 = __builtin_amdgcn_fdot2(w1b[k],     h1h[k],     a2B0, false);
            a2B1 = __builtin_amdgcn_fdot2(w1b[k + 8], h1h[k + 8], a2B1, false);
            a2B2 = __builtin_amdgcn_fdot2(w2b[k],     h2h[k],     a2B2, false);
            a2B3 = __builtin_amdgcn_fdot2(w2b[k + 8], h2h[k + 8], a2B3, false);
        }
        const float nh2A = fmaxf((a2A0 + a2A1) + (a2A2 + a2A3), 0.f);
        const float nh2B = fmaxf((a2B0 + a2B1) + (a2B2 + a2B3), 0.f);
        __syncthreads();
        h2v p2; p2[0] = (_Float16)nh2A; p2[1] = (_Float16)nh2B;
        *(h2v*)&hs[bs][H_ + 2 * u] = p2;
    }
    __syncthreads();

    // ---- FC head: lane u<9 computes class u for batch bs ----
    if (u < NC_) {
        float acc = b_fc[u];
#pragma unroll
        for (int k = 0; k < H_; ++k)
            acc = fmaf(W_fc[u * H_ + k], (float)hs[bs][H_ + k], acc);
        out[b * NC_ + u] = acc;
    }
}

extern "C" void kernel_launch(void* const* d_in, const int* in_sizes, int n_in,
                              void* d_out, int out_size, void* d_ws, size_t ws_size,
                              hipStream_t stream) {
    const float* x     = (const float*)d_in[0];
    const float* W_ih0 = (const float*)d_in[1];
    const float* W_hh0 = (const float*)d_in[2];
    const float* b_ih0 = (const float*)d_in[3];
    const float* b_hh0 = (const float*)d_in[4];
    const float* W_ih1 = (const float*)d_in[5];
    const float* W_hh1 = (const float*)d_in[6];
    const float* b_ih1 = (const float*)d_in[7];
    const float* b_hh1 = (const float*)d_in[8];
    const float* W_fc  = (const float*)d_in[9];
    const float* b_fc  = (const float*)d_in[10];
    float* out = (float*)d_out;

    const int B = in_sizes[0] / (T_ * IN_);   // 4096
    gesture_rnn_kernel<<<dim3(B / 4), dim3(64), 0, stream>>>(
        x, W_ih0, W_hh0, b_ih0, b_hh0, W_ih1, W_hh1, b_ih1, b_hh1,
        W_fc, b_fc, out);
}

// Round 8
// 275.902 us; speedup vs baseline: 1.8678x; 1.1864x over previous
//
#include <hip/hip_runtime.h>

// GestureRNN v8: v7 layout + x tiled through LDS + fenceless steps.
// B=4096, T=512, IN=10, H=32, NCLS=9.
//
// v7 post-mortem: v5 (2 waves/SIMD x 2 batch) and v7 (1 wave/SIMD x 4 batch)
// both pin at ~1100 cyc/step -> latency-bound, not issue-bound. The dominant
// segment: __syncthreads() emits s_waitcnt vmcnt(0) before s_barrier, so every
// step DRAINS the in-flight x global prefetch (~half HBM misses, ~900 cyc).
// v8 removes both: (1) x is staged per-16-step tile: lane u loads timestep
// t0+u of its batch into regs a full tile (~5600 cyc) ahead, dumps to LDS at
// tile boundary; steps read x from LDS (broadcast, bank-disjoint). No global
// access on the step chain. (2) steps end with a compiler-only fence; the
// per-wave in-order DS pipe provides LDS RAW within a single-wave block
// (correctness proven by v6's fenceless variant).
// Core: 4 batches/wave, lane owns units {2u,2u+1}, f16 state + v_dot2_f32_f16,
// layer-pipelined (step t computes h1[t] and h2[t-1]).

constexpr int T_  = 512;
constexpr int IN_ = 10;
constexpr int H_  = 32;
constexpr int NC_ = 9;
constexpr int SP_ = 96;    // state stride per batch, f16 elems (192 B):
                           // h1 at [0..31], h2 at [64..95] -> write banks
                           // uniform 2-way (free), reads 2-way broadcast.
constexpr int XS_ = 12;    // x slot stride, floats (48 B, 16B-aligned slots)
constexpr int XB_ = 196;   // x buffer per batch, floats (16*12 + 4 pad = 784 B)
constexpr int XT_ = 16;    // timesteps per x tile

typedef _Float16 h2v __attribute__((ext_vector_type(2)));
union U4H { uint4 u; h2v h[4]; };

__device__ __forceinline__ void cfence() { __asm__ volatile("" ::: "memory"); }

__global__ __launch_bounds__(64, 1) void gesture_rnn_kernel(
    const float* __restrict__ x,      // [B, T, IN]
    const float* __restrict__ W_ih0,  // [H, IN]
    const float* __restrict__ W_hh0,  // [H, H]
    const float* __restrict__ b_ih0,  // [H]
    const float* __restrict__ b_hh0,  // [H]
    const float* __restrict__ W_ih1,  // [H, H]
    const float* __restrict__ W_hh1,  // [H, H]
    const float* __restrict__ b_ih1,  // [H]
    const float* __restrict__ b_hh1,  // [H]
    const float* __restrict__ W_fc,   // [NC, H]
    const float* __restrict__ b_fc,   // [NC]
    float* __restrict__ out)          // [B, NC]
{
    const int lane = threadIdx.x;     // 0..63
    const int bs   = lane >> 4;       // batch slot within wave: 0..3
    const int u    = lane & 15;       // unit-pair index: owns units 2u, 2u+1
    const long b   = (long)blockIdx.x * 4 + bs;
    const int jA   = 2 * u, jB = 2 * u + 1;

    // ---- fp32 x-projection weights for both owned units ----
    float wxA[IN_], wxB[IN_];
#pragma unroll
    for (int i = 0; i < IN_; ++i) {
        wxA[i] = W_ih0[jA * IN_ + i];
        wxB[i] = W_ih0[jB * IN_ + i];
    }

    // ---- half2-packed recurrent weight rows for units jA, jB ----
    h2v w0a[16], w0b[16], w1a[16], w1b[16], w2a[16], w2b[16];
#pragma unroll
    for (int k = 0; k < 16; ++k) {
        w0a[k][0] = (_Float16)W_hh0[jA * H_ + 2 * k];
        w0a[k][1] = (_Float16)W_hh0[jA * H_ + 2 * k + 1];
        w0b[k][0] = (_Float16)W_hh0[jB * H_ + 2 * k];
        w0b[k][1] = (_Float16)W_hh0[jB * H_ + 2 * k + 1];
        w1a[k][0] = (_Float16)W_ih1[jA * H_ + 2 * k];
        w1a[k][1] = (_Float16)W_ih1[jA * H_ + 2 * k + 1];
        w1b[k][0] = (_Float16)W_ih1[jB * H_ + 2 * k];
        w1b[k][1] = (_Float16)W_ih1[jB * H_ + 2 * k + 1];
        w2a[k][0] = (_Float16)W_hh1[jA * H_ + 2 * k];
        w2a[k][1] = (_Float16)W_hh1[jA * H_ + 2 * k + 1];
        w2b[k][0] = (_Float16)W_hh1[jB * H_ + 2 * k];
        w2b[k][1] = (_Float16)W_hh1[jB * H_ + 2 * k + 1];
    }
    const float bias0A = b_ih0[jA] + b_hh0[jA];
    const float bias0B = b_ih0[jB] + b_hh0[jB];
    const float bias1A = b_ih1[jA] + b_hh1[jA];
    const float bias1B = b_ih1[jB] + b_hh1[jB];

    __shared__ __align__(16) _Float16 hs[4][SP_];     // recurrent state
    __shared__ __align__(16) float xtile[4][XB_];     // current x tile

    // ---- x tile machinery: lane u owns timestep (16*nt + u) of batch b ----
    const float* xg = x + ((size_t)b * T_ + u) * IN_;
    float xr[IN_];
#pragma unroll
    for (int i = 0; i < IN_; i += 2) {                // load tile 0
        float2 v = *(const float2*)(xg + i);
        xr[i] = v.x; xr[i + 1] = v.y;
    }
    xg += XT_ * IN_;

#define STAGE(PREFETCH)                                                      \
    {                                                                        \
        float* dst_ = &xtile[bs][u * XS_];                                   \
        *(float4*)(dst_)     = make_float4(xr[0], xr[1], xr[2], xr[3]);      \
        *(float4*)(dst_ + 4) = make_float4(xr[4], xr[5], xr[6], xr[7]);      \
        *(float2*)(dst_ + 8) = make_float2(xr[8], xr[9]);                    \
        if (PREFETCH) {                                                      \
            _Pragma("unroll")                                                \
            for (int i_ = 0; i_ < IN_; i_ += 2) {                            \
                float2 v_ = *(const float2*)(xg + i_);                       \
                xr[i_] = v_.x; xr[i_ + 1] = v_.y;                            \
            }                                                                \
            xg += XT_ * IN_;                                                 \
        }                                                                    \
        cfence();                                                            \
    }

#define STEP(TT)                                                             \
    {                                                                        \
        const uint4* sp_ = (const uint4*)&hs[bs][0];                         \
        h2v h1h[16], h2h[16];                                                \
        _Pragma("unroll")                                                    \
        for (int q_ = 0; q_ < 4; ++q_) {                                     \
            U4H a_; a_.u = sp_[q_];                                          \
            U4H c_; c_.u = sp_[q_ + 8];                                      \
            _Pragma("unroll")                                                \
            for (int r_ = 0; r_ < 4; ++r_) {                                 \
                h1h[4 * q_ + r_] = a_.h[r_];                                 \
                h2h[4 * q_ + r_] = c_.h[r_];                                 \
            }                                                                \
        }                                                                    \
        const float* xs_ = &xtile[bs][((TT) & 15) * XS_];                    \
        const float4 xv0_ = *(const float4*)(xs_);                           \
        const float4 xv1_ = *(const float4*)(xs_ + 4);                       \
        const float2 xv2_ = *(const float2*)(xs_ + 8);                       \
        const float xvv_[10] = {xv0_.x, xv0_.y, xv0_.z, xv0_.w,              \
                                xv1_.x, xv1_.y, xv1_.z, xv1_.w,              \
                                xv2_.x, xv2_.y};                             \
        float a1A0 = bias0A, a1A1 = 0.f, a1B0 = bias0B, a1B1 = 0.f;          \
        _Pragma("unroll")                                                    \
        for (int i_ = 0; i_ < IN_; i_ += 2) {                                \
            a1A0 = fmaf(wxA[i_],     xvv_[i_],     a1A0);                    \
            a1A1 = fmaf(wxA[i_ + 1], xvv_[i_ + 1], a1A1);                    \
            a1B0 = fmaf(wxB[i_],     xvv_[i_],     a1B0);                    \
            a1B1 = fmaf(wxB[i_ + 1], xvv_[i_ + 1], a1B1);                    \
        }                                                                    \
        float a2A0 = bias1A, a2A1 = 0.f, a2A2 = 0.f, a2A3 = 0.f;             \
        float a2B0 = bias1B, a2B1 = 0.f, a2B2 = 0.f, a2B3 = 0.f;             \
        _Pragma("unroll")                                                    \
        for (int k_ = 0; k_ < 8; ++k_) {                                     \
            a1A0 = __builtin_amdgcn_fdot2(w0a[k_],   h1h[k_],   a1A0, false);\
            a1A1 = __builtin_amdgcn_fdot2(w0a[k_+8], h1h[k_+8], a1A1, false);\
            a1B0 = __builtin_amdgcn_fdot2(w0b[k_],   h1h[k_],   a1B0, false);\
            a1B1 = __builtin_amdgcn_fdot2(w0b[k_+8], h1h[k_+8], a1B1, false);\
            a2A0 = __builtin_amdgcn_fdot2(w1a[k_],   h1h[k_],   a2A0, false);\
            a2A1 = __builtin_amdgcn_fdot2(w1a[k_+8], h1h[k_+8], a2A1, false);\
            a2A2 = __builtin_amdgcn_fdot2(w2a[k_],   h2h[k_],   a2A2, false);\
            a2A3 = __builtin_amdgcn_fdot2(w2a[k_+8], h2h[k_+8], a2A3, false);\
            a2B0 = __builtin_amdgcn_fdot2(w1b[k_],   h1h[k_],   a2B0, false);\
            a2B1 = __builtin_amdgcn_fdot2(w1b[k_+8], h1h[k_+8], a2B1, false);\
            a2B2 = __builtin_amdgcn_fdot2(w2b[k_],   h2h[k_],   a2B2, false);\
            a2B3 = __builtin_amdgcn_fdot2(w2b[k_+8], h2h[k_+8], a2B3, false);\
        }                                                                    \
        const float nh1A = fmaxf(a1A0 + a1A1, 0.f);                          \
        const float nh1B = fmaxf(a1B0 + a1B1, 0.f);                          \
        const float nh2A = fmaxf((a2A0 + a2A1) + (a2A2 + a2A3), 0.f);        \
        const float nh2B = fmaxf((a2B0 + a2B1) + (a2B2 + a2B3), 0.f);        \
        h2v p1_; p1_[0] = (_Float16)nh1A; p1_[1] = (_Float16)nh1B;           \
        h2v p2_; p2_[0] = (_Float16)nh2A; p2_[1] = (_Float16)nh2B;           \
        *(h2v*)&hs[bs][2 * u]      = p1_;                                    \
        *(h2v*)&hs[bs][64 + 2 * u] = p2_;                                    \
        cfence();                                                            \
    }

    // ---- stage tile 0 into LDS, prefetch tile 1 ----
    STAGE(1);

    // ---- prologue t=0: h1[0] = relu(xproj(x[0])), h2[-1] = 0 ----
    {
        const float* xs = &xtile[bs][0];
        const float4 xv0 = *(const float4*)(xs);
        const float4 xv1 = *(const float4*)(xs + 4);
        const float2 xv2 = *(const float2*)(xs + 8);
        const float xvv[10] = {xv0.x, xv0.y, xv0.z, xv0.w,
                               xv1.x, xv1.y, xv1.z, xv1.w, xv2.x, xv2.y};
        float aA = bias0A, aB = bias0B;
#pragma unroll
        for (int i = 0; i < IN_; ++i) {
            aA = fmaf(wxA[i], xvv[i], aA);
            aB = fmaf(wxB[i], xvv[i], aB);
        }
        h2v p; p[0] = (_Float16)fmaxf(aA, 0.f); p[1] = (_Float16)fmaxf(aB, 0.f);
        h2v z; z[0] = (_Float16)0.f; z[1] = (_Float16)0.f;
        *(h2v*)&hs[bs][2 * u]      = p;
        *(h2v*)&hs[bs][64 + 2 * u] = z;
        cfence();
    }

    // ---- steps 1..15 (tile 0) ----
#pragma unroll 5
    for (int r = 1; r < 16; ++r) STEP(r);

    // ---- tiles 1..31 ----
#pragma unroll 1
    for (int nt = 1; nt < 32; ++nt) {
        STAGE(nt < 31);
#pragma unroll 4
        for (int r = 0; r < 16; ++r) STEP(16 * nt + r);
    }

    // ---- epilogue: h2[511] = relu(bias1 + W_ih1.h1[511] + W_hh1.h2[510]) ----
    {
        const uint4* sp = (const uint4*)&hs[bs][0];
        h2v h1h[16], h2h[16];
#pragma unroll
        for (int q = 0; q < 4; ++q) {
            U4H a; a.u = sp[q];
            U4H c; c.u = sp[q + 8];
#pragma unroll
            for (int r = 0; r < 4; ++r) {
                h1h[4 * q + r] = a.h[r];
                h2h[4 * q + r] = c.h[r];
            }
        }
        float a2A0 = bias1A, a2A1 = 0.f, a2A2 = 0.f, a2A3 = 0.f;
        float a2B0 = bias1B, a2B1 = 0.f, a2B2 = 0.f, a2B3 = 0.f;
#pragma unroll
        for (int k = 0; k < 8; ++k) {
            a2A0 = __builtin_amdgcn_fdot2(w1a[k],     h1h[k],     a2A0, false);
            a2A1 = __builtin_amdgcn_fdot2(w1a[k + 8], h1h[k + 8], a2A1, false);
            a2A2 = __builtin_amdgcn_fdot2(w2a[k],     h2h[k],     a2A2, false);
            a2A3 = __builtin_amdgcn_fdot2(w2a[k + 8], h2h[k + 8], a2A3, false);
            a2B0 = __builtin_amdgcn_fdot2(w1b[k],     h1h[k],     a2B0, false);
            a2B1 = __builtin_amdgcn_fdot2(w1b[k + 8], h1h[k + 8], a2B1, false);
            a2B2 = __builtin_amdgcn_fdot2(w2b[k],     h2h[k],     a2B2, false);
            a2B3 = __builtin_amdgcn_fdot2(w2b[k + 8], h2h[k + 8], a2B3, false);
        }
        const float nh2A = fmaxf((a2A0 + a2A1) + (a2A2 + a2A3), 0.f);
        const float nh2B = fmaxf((a2B0 + a2B1) + (a2B2 + a2B3), 0.f);
        h2v p2; p2[0] = (_Float16)nh2A; p2[1] = (_Float16)nh2B;
        *(h2v*)&hs[bs][64 + 2 * u] = p2;
        cfence();
    }

    // ---- FC head: lane u<9 computes class u for batch bs ----
    if (u < NC_) {
        float acc = b_fc[u];
#pragma unroll
        for (int k = 0; k < H_; ++k)
            acc = fmaf(W_fc[u * H_ + k], (float)hs[bs][64 + k], acc);
        out[b * NC_ + u] = acc;
    }
#undef STAGE
#undef STEP
}

extern "C" void kernel_launch(void* const* d_in, const int* in_sizes, int n_in,
                              void* d_out, int out_size, void* d_ws, size_t ws_size,
                              hipStream_t stream) {
    const float* x     = (const float*)d_in[0];
    const float* W_ih0 = (const float*)d_in[1];
    const float* W_hh0 = (const float*)d_in[2];
    const float* b_ih0 = (const float*)d_in[3];
    const float* b_hh0 = (const float*)d_in[4];
    const float* W_ih1 = (const float*)d_in[5];
    const float* W_hh1 = (const float*)d_in[6];
    const float* b_ih1 = (const float*)d_in[7];
    const float* b_hh1 = (const float*)d_in[8];
    const float* W_fc  = (const float*)d_in[9];
    const float* b_fc  = (const float*)d_in[10];
    float* out = (float*)d_out;

    const int B = in_sizes[0] / (T_ * IN_);   // 4096
    gesture_rnn_kernel<<<dim3(B / 4), dim3(64), 0, stream>>>(
        x, W_ih0, W_hh0, b_ih0, b_hh0, W_ih1, W_hh1, b_ih1, b_hh1,
        W_fc, b_fc, out);
}